// Round 4
// baseline (16402.559 us; speedup 1.0000x reference)
//
#include <hip/hip_runtime.h>
#include <hip/hip_fp16.h>
#include <cstdint>

#define B_SZ 4
#define T_SZ 512
#define D_SZ 768
#define H_SZ 768
#define G4   3072           // 4*H
#define V_SZ 50257
#define V_PAD 50304         // 393*128
#define M_SZ 2048           // T*B
#define SCAN_WGS 96

using half8 = __attribute__((ext_vector_type(8))) _Float16;
using f32x4 = __attribute__((ext_vector_type(4))) float;

// ---------------- conversion kernels ----------------

__global__ void conv_A0(const float* __restrict__ reps, _Float16* __restrict__ A0) {
  // A0[(t*4+b)*768 + k] = reps[(b*512 + t)*768 + k]
  int idx = blockIdx.x * blockDim.x + threadIdx.x;
  const int total = M_SZ * D_SZ;
  for (; idx < total; idx += gridDim.x * blockDim.x) {
    int k = idx % D_SZ, m = idx / D_SZ;
    int t = m >> 2, b = m & 3;
    A0[idx] = (_Float16)reps[(b * T_SZ + t) * D_SZ + k];
  }
}

__global__ void conv_cast(const float* __restrict__ src, _Float16* __restrict__ dst, int n) {
  int idx = blockIdx.x * blockDim.x + threadIdx.x;
  for (; idx < n; idx += gridDim.x * blockDim.x) dst[idx] = (_Float16)src[idx];
}

__global__ void conv_head(const float* __restrict__ w, _Float16* __restrict__ dst) {
  int idx = blockIdx.x * blockDim.x + threadIdx.x;
  const int total = V_PAD * H_SZ;
  for (; idx < total; idx += gridDim.x * blockDim.x) {
    int n = idx / H_SZ, k = idx % H_SZ;
    dst[idx] = (n < V_SZ) ? (_Float16)w[n * H_SZ + k] : (_Float16)0.f;
  }
}

// ---------------- f16 MFMA GEMM: C[m][n] = sum_k A[m][k]*B[n][k] + bias[n] ----------------
// A: M x K fp16 row-major, B: N x K fp16 row-major ("B^T input" form).
// mode 0: C row-major M x N fp32.  mode 1: head output C[(b*T + t)*V_SZ + n], m = t*4+b, guard n < Nreal.

__global__ __launch_bounds__(256) void gemm_bt_f16(
    const _Float16* __restrict__ A, const _Float16* __restrict__ B,
    const float* __restrict__ bias, float* __restrict__ C,
    int M, int N, int K, int mode, int Nreal)
{
  __shared__ __align__(16) _Float16 As[128][32];
  __shared__ __align__(16) _Float16 Bs[128][32];
  const int t = threadIdx.x;
  const int lane = t & 63, w = t >> 6;
  const int wr = w >> 1, wc = w & 1;
  const int m0 = blockIdx.x * 128, n0 = blockIdx.y * 128;

  f32x4 acc[4][4] = {};

  const int srow = t >> 2;            // 0..63
  const int scol = (t & 3) * 8;       // half-element offset within 32

  for (int k0 = 0; k0 < K; k0 += 32) {
    uint4 av0 = *(const uint4*)&A[(size_t)(m0 + srow) * K + k0 + scol];
    uint4 av1 = *(const uint4*)&A[(size_t)(m0 + 64 + srow) * K + k0 + scol];
    uint4 bv0 = *(const uint4*)&B[(size_t)(n0 + srow) * K + k0 + scol];
    uint4 bv1 = *(const uint4*)&B[(size_t)(n0 + 64 + srow) * K + k0 + scol];
    __syncthreads();                  // previous iter's frag reads done
    *(uint4*)&As[srow][scol]      = av0;
    *(uint4*)&As[64 + srow][scol] = av1;
    *(uint4*)&Bs[srow][scol]      = bv0;
    *(uint4*)&Bs[64 + srow][scol] = bv1;
    __syncthreads();

    const int fr = lane & 15, k8 = (lane >> 4) * 8;
    half8 af[4], bf[4];
#pragma unroll
    for (int i = 0; i < 4; ++i) {
      af[i] = *(const half8*)&As[wr * 64 + i * 16 + fr][k8];
      bf[i] = *(const half8*)&Bs[wc * 64 + i * 16 + fr][k8];
    }
#pragma unroll
    for (int i = 0; i < 4; ++i)
#pragma unroll
      for (int j = 0; j < 4; ++j)
        acc[i][j] = __builtin_amdgcn_mfma_f32_16x16x32_f16(af[i], bf[j], acc[i][j], 0, 0, 0);
  }

  const int fr = lane & 15, rq = lane >> 4;
#pragma unroll
  for (int i = 0; i < 4; ++i) {
#pragma unroll
    for (int j = 0; j < 4; ++j) {
      int n = n0 + wc * 64 + j * 16 + fr;
      if (n >= Nreal) continue;
      float bv = bias[n];
#pragma unroll
      for (int r = 0; r < 4; ++r) {
        int m = m0 + wr * 64 + i * 16 + rq * 4 + r;
        float v = acc[i][j][r] + bv;
        if (mode == 0) {
          C[(size_t)m * N + n] = v;
        } else {
          int tt = m >> 2, bb = m & 3;
          C[(size_t)(bb * T_SZ + tt) * V_SZ + n] = v;
        }
      }
    }
  }
}

// ---------------- persistent LSTM scan (one layer), plain launch ----------------
// 96 WGs x 256 threads (co-resident by capacity on 256 CUs).
// Distributed-flag grid barrier: EVERY block (incl. 0) release-stores
// flags[blockIdx.x*32] = step+1 (own 128B line, no RMW contention);
// block 0 threads 0..95 poll one flag each, then thread 0 release-stores
// gen = step+1; other blocks poll gen. Monotone values; memset 0 per launch.

__device__ __forceinline__ void grid_barrier(unsigned* flags, unsigned* gen, unsigned target) {
  __syncthreads();   // all compute writes of this block drained
  const int t = threadIdx.x;
  if (t == 0) {
    __threadfence();   // release our block's writes
    __hip_atomic_store(&flags[blockIdx.x * 32], target, __ATOMIC_RELEASE, __HIP_MEMORY_SCOPE_AGENT);
  }
  if (blockIdx.x == 0) {
    if (t < SCAN_WGS) {
      while (__hip_atomic_load(&flags[t * 32], __ATOMIC_ACQUIRE, __HIP_MEMORY_SCOPE_AGENT) < target)
        __builtin_amdgcn_s_sleep(1);
      __threadfence();                                 // acquire others' writes
    }
    __syncthreads();
    if (t == 0)
      __hip_atomic_store(gen, target, __ATOMIC_RELEASE, __HIP_MEMORY_SCOPE_AGENT);
  } else {
    if (t == 0) {
      while (__hip_atomic_load(gen, __ATOMIC_ACQUIRE, __HIP_MEMORY_SCOPE_AGENT) < target)
        __builtin_amdgcn_s_sleep(1);
      __threadfence();                                 // acquire others' writes
    }
  }
  __syncthreads();
}

__global__ __launch_bounds__(256) void lstm_scan(
    const float* __restrict__ xg,     // (2048, 3072): row = t*4+b
    const float* __restrict__ Whh,    // (3072, 768) fp32
    float* __restrict__ hstate,       // 2 * 3072 floats, (k,b) layout, pre-zeroed
    _Float16* __restrict__ hist,      // (2048, 768) fp16, row = t*4+b
    unsigned* __restrict__ bar)       // flags[96*32] + gen at [3072], pre-zeroed
{
  __shared__ __align__(16) float hbuf[H_SZ * 4];   // [k][b]
  __shared__ __align__(16) float red[4][8][4][4];  // [gate][c][q][b]
  __shared__ float actv[4][8][4];                  // [gate][c][b]
  __shared__ float cst[8][4];

  const int t = threadIdx.x, lane = t & 63, wv = t >> 6;
  const int j0 = blockIdx.x * 8;
  unsigned* flags = bar;
  unsigned* gen = bar + 3072;

  // preload W_hh slice into registers: w[c][kk] = Whh[wv*768 + j0 + c][kk*64 + lane]
  float wreg[8][12];
#pragma unroll
  for (int c = 0; c < 8; ++c)
#pragma unroll
    for (int kk = 0; kk < 12; ++kk)
      wreg[c][kk] = Whh[(size_t)(wv * H_SZ + j0 + c) * H_SZ + kk * 64 + lane];

  if (t < 32) cst[t >> 2][t & 3] = 0.f;

  const int g_ = t >> 5, c_ = (t >> 2) & 7, b_ = t & 3;

  for (int step = 0; step < T_SZ; ++step) {
    float xgv = 0.f;
    if (t < 128)  // prefetch xg before the barrier (independent of h)
      xgv = xg[(size_t)((step << 2) + b_) * G4 + g_ * H_SZ + j0 + c_];

    grid_barrier(flags, gen, (unsigned)(step + 1));

    const float* hprev = hstate + ((step & 1) ? 3072 : 0);
    {
      const float4* s4 = (const float4*)hprev;
      float4* d4 = (float4*)hbuf;
#pragma unroll
      for (int i = 0; i < 3; ++i) d4[i * 256 + t] = s4[i * 256 + t];
    }
    __syncthreads();

    float4 acc[8];
#pragma unroll
    for (int c = 0; c < 8; ++c) acc[c] = make_float4(0.f, 0.f, 0.f, 0.f);
#pragma unroll
    for (int kk = 0; kk < 12; ++kk) {
      float4 h4 = *(const float4*)&hbuf[(kk * 64 + lane) * 4];
#pragma unroll
      for (int c = 0; c < 8; ++c) {
        float wf = wreg[c][kk];
        acc[c].x = fmaf(wf, h4.x, acc[c].x);
        acc[c].y = fmaf(wf, h4.y, acc[c].y);
        acc[c].z = fmaf(wf, h4.z, acc[c].z);
        acc[c].w = fmaf(wf, h4.w, acc[c].w);
      }
    }
    // butterfly reduce within aligned 16-lane groups
#pragma unroll
    for (int mask = 1; mask <= 8; mask <<= 1) {
#pragma unroll
      for (int c = 0; c < 8; ++c) {
        acc[c].x += __shfl_xor(acc[c].x, mask, 64);
        acc[c].y += __shfl_xor(acc[c].y, mask, 64);
        acc[c].z += __shfl_xor(acc[c].z, mask, 64);
        acc[c].w += __shfl_xor(acc[c].w, mask, 64);
      }
    }
    if ((lane & 15) == 0) {
      int q = lane >> 4;
#pragma unroll
      for (int c = 0; c < 8; ++c) *(float4*)&red[wv][c][q][0] = acc[c];
    }
    __syncthreads();

    if (t < 128) {
      float s = red[g_][c_][0][b_] + red[g_][c_][1][b_] + red[g_][c_][2][b_] + red[g_][c_][3][b_] + xgv;
      float a;
      if (g_ == 2) a = tanhf(s);
      else         a = 1.f / (1.f + expf(-s));
      actv[g_][c_][b_] = a;
    }
    __syncthreads();

    if (t < 32) {
      int c = t >> 2, b = t & 3;
      float iv = actv[0][c][b], fv = actv[1][c][b], gv = actv[2][c][b], ov = actv[3][c][b];
      float cn = fv * cst[c][b] + iv * gv;
      cst[c][b] = cn;
      float hn = ov * tanhf(cn);
      float* hnext = hstate + (((step + 1) & 1) ? 3072 : 0);
      hnext[(j0 + c) * 4 + b] = hn;
      hist[(size_t)((step << 2) + b) * H_SZ + j0 + c] = (_Float16)hn;
    }
    // next iteration's grid_barrier provides the ordering before re-reads
  }
}

// ---------------- launcher ----------------

extern "C" void kernel_launch(void* const* d_in, const int* in_sizes, int n_in,
                              void* d_out, int out_size, void* d_ws, size_t ws_size,
                              hipStream_t stream) {
  const float* reps   = (const float*)d_in[0];
  const float* W_ih   = (const float*)d_in[1];
  const float* W_hh   = (const float*)d_in[2];
  const float* bias   = (const float*)d_in[3];
  const float* head_w = (const float*)d_in[4];
  const float* head_b = (const float*)d_in[5];
  float* out = (float*)d_out;

  char* ws = (char*)d_ws;
  _Float16* A0h    = (_Float16*)(ws + 0);            //  3,145,728 B
  _Float16* Wih_h  = (_Float16*)(ws + 3145728);      //  9,437,184 B (both layers)
  _Float16* Whead  = (_Float16*)(ws + 12582912);     // 77,266,944 B (padded)
  float*    xg     = (float*)   (ws + 89849856);     // 25,165,824 B (reused for both layers)
  _Float16* h0hist = (_Float16*)(ws + 115015680);    //  3,145,728 B
  _Float16* h1hist = (_Float16*)(ws + 118161408);    //  3,145,728 B
  float*    hstate = (float*)   (ws + 121307136);    //     24,576 B
  unsigned* bar    = (unsigned*)(ws + 121331712);    //     12,416 B (flags 96*128B + gen)

  // conversions
  hipLaunchKernelGGL(conv_A0,   dim3(1024), dim3(256), 0, stream, reps, A0h);
  hipLaunchKernelGGL(conv_cast, dim3(2048), dim3(256), 0, stream, W_ih, Wih_h, 2 * G4 * H_SZ);
  hipLaunchKernelGGL(conv_head, dim3(4096), dim3(256), 0, stream, head_w, Whead);

  // xg0 = A0 * Wih0^T + b0
  hipLaunchKernelGGL(gemm_bt_f16, dim3(16, 24), dim3(256), 0, stream,
                     A0h, Wih_h, bias, xg, M_SZ, G4, H_SZ, 0, G4);

  // layer 0 scan (plain launch; 96 blocks co-resident by capacity)
  hipMemsetAsync(hstate, 0, 24576, stream);
  hipMemsetAsync(bar, 0, 12416, stream);
  hipLaunchKernelGGL(lstm_scan, dim3(SCAN_WGS), dim3(256), 0, stream,
                     xg, W_hh, hstate, h0hist, bar);

  // xg1 = h0 * Wih1^T + b1
  hipLaunchKernelGGL(gemm_bt_f16, dim3(16, 24), dim3(256), 0, stream,
                     h0hist, Wih_h + (size_t)G4 * H_SZ, bias + G4, xg, M_SZ, G4, H_SZ, 0, G4);

  // layer 1 scan
  hipMemsetAsync(hstate, 0, 24576, stream);
  hipMemsetAsync(bar, 0, 12416, stream);
  hipLaunchKernelGGL(lstm_scan, dim3(SCAN_WGS), dim3(256), 0, stream,
                     xg, W_hh + (size_t)G4 * H_SZ, hstate, h1hist, bar);

  // logits = h1 * head_w^T + head_b  (padded N, permuted store into (B,T,V))
  hipLaunchKernelGGL(gemm_bt_f16, dim3(16, 393), dim3(256), 0, stream,
                     h1hist, Whead, head_b, out, M_SZ, V_PAD, H_SZ, 1, V_SZ);
}

// Round 5
// 8754.072 us; speedup vs baseline: 1.8737x; 1.8737x over previous
//
#include <hip/hip_runtime.h>
#include <hip/hip_fp16.h>
#include <cstdint>

#define B_SZ 4
#define T_SZ 512
#define D_SZ 768
#define H_SZ 768
#define G4   3072           // 4*H
#define V_SZ 50257
#define V_PAD 50304         // 393*128
#define M_SZ 2048           // T*B
#define SCAN_WGS 96

using half8 = __attribute__((ext_vector_type(8))) _Float16;
using f32x4 = __attribute__((ext_vector_type(4))) float;

// ---------------- conversion kernels ----------------

__global__ void conv_A0(const float* __restrict__ reps, _Float16* __restrict__ A0) {
  // A0[(t*4+b)*768 + k] = reps[(b*512 + t)*768 + k]
  int idx = blockIdx.x * blockDim.x + threadIdx.x;
  const int total = M_SZ * D_SZ;
  for (; idx < total; idx += gridDim.x * blockDim.x) {
    int k = idx % D_SZ, m = idx / D_SZ;
    int t = m >> 2, b = m & 3;
    A0[idx] = (_Float16)reps[(b * T_SZ + t) * D_SZ + k];
  }
}

__global__ void conv_cast(const float* __restrict__ src, _Float16* __restrict__ dst, int n) {
  int idx = blockIdx.x * blockDim.x + threadIdx.x;
  for (; idx < n; idx += gridDim.x * blockDim.x) dst[idx] = (_Float16)src[idx];
}

__global__ void conv_head(const float* __restrict__ w, _Float16* __restrict__ dst) {
  int idx = blockIdx.x * blockDim.x + threadIdx.x;
  const int total = V_PAD * H_SZ;
  for (; idx < total; idx += gridDim.x * blockDim.x) {
    int n = idx / H_SZ, k = idx % H_SZ;
    dst[idx] = (n < V_SZ) ? (_Float16)w[n * H_SZ + k] : (_Float16)0.f;
  }
}

// ---------------- f16 MFMA GEMM: C[m][n] = sum_k A[m][k]*B[n][k] + bias[n] ----------------
// A: M x K fp16 row-major, B: N x K fp16 row-major ("B^T input" form).
// mode 0: C row-major M x N fp32.  mode 1: head output C[(b*T + t)*V_SZ + n], m = t*4+b, guard n < Nreal.

__global__ __launch_bounds__(256) void gemm_bt_f16(
    const _Float16* __restrict__ A, const _Float16* __restrict__ B,
    const float* __restrict__ bias, float* __restrict__ C,
    int M, int N, int K, int mode, int Nreal)
{
  __shared__ __align__(16) _Float16 As[128][32];
  __shared__ __align__(16) _Float16 Bs[128][32];
  const int t = threadIdx.x;
  const int lane = t & 63, w = t >> 6;
  const int wr = w >> 1, wc = w & 1;
  const int m0 = blockIdx.x * 128, n0 = blockIdx.y * 128;

  f32x4 acc[4][4] = {};

  const int srow = t >> 2;            // 0..63
  const int scol = (t & 3) * 8;       // half-element offset within 32

  for (int k0 = 0; k0 < K; k0 += 32) {
    uint4 av0 = *(const uint4*)&A[(size_t)(m0 + srow) * K + k0 + scol];
    uint4 av1 = *(const uint4*)&A[(size_t)(m0 + 64 + srow) * K + k0 + scol];
    uint4 bv0 = *(const uint4*)&B[(size_t)(n0 + srow) * K + k0 + scol];
    uint4 bv1 = *(const uint4*)&B[(size_t)(n0 + 64 + srow) * K + k0 + scol];
    __syncthreads();                  // previous iter's frag reads done
    *(uint4*)&As[srow][scol]      = av0;
    *(uint4*)&As[64 + srow][scol] = av1;
    *(uint4*)&Bs[srow][scol]      = bv0;
    *(uint4*)&Bs[64 + srow][scol] = bv1;
    __syncthreads();

    const int fr = lane & 15, k8 = (lane >> 4) * 8;
    half8 af[4], bf[4];
#pragma unroll
    for (int i = 0; i < 4; ++i) {
      af[i] = *(const half8*)&As[wr * 64 + i * 16 + fr][k8];
      bf[i] = *(const half8*)&Bs[wc * 64 + i * 16 + fr][k8];
    }
#pragma unroll
    for (int i = 0; i < 4; ++i)
#pragma unroll
      for (int j = 0; j < 4; ++j)
        acc[i][j] = __builtin_amdgcn_mfma_f32_16x16x32_f16(af[i], bf[j], acc[i][j], 0, 0, 0);
  }

  const int fr = lane & 15, rq = lane >> 4;
#pragma unroll
  for (int i = 0; i < 4; ++i) {
#pragma unroll
    for (int j = 0; j < 4; ++j) {
      int n = n0 + wc * 64 + j * 16 + fr;
      if (n >= Nreal) continue;
      float bv = bias[n];
#pragma unroll
      for (int r = 0; r < 4; ++r) {
        int m = m0 + wr * 64 + i * 16 + rq * 4 + r;
        float v = acc[i][j][r] + bv;
        if (mode == 0) {
          C[(size_t)m * N + n] = v;
        } else {
          int tt = m >> 2, bb = m & 3;
          C[(size_t)(bb * T_SZ + tt) * V_SZ + n] = v;
        }
      }
    }
  }
}

// ---------------- persistent LSTM scan (one layer), plain launch ----------------
// 96 WGs x 256 threads (co-resident by capacity on 256 CUs).
// Distributed-flag grid barrier with RELAXED polling:
//  - release: __threadfence() (wbl2: prior writes reach MALL) then RELAXED
//    flag store (sc1 write-through, no extra maintenance).
//  - poll: RELAXED agent-scope loads (sc1 -> read coherence point directly,
//    NO per-iteration buffer_inv). One __threadfence() (acquire/inv) after
//    the loop exits, before any hstate reads.
// Flags monotone (step+1); memset 0 before each scan launch.

__device__ __forceinline__ void grid_barrier(unsigned* flags, unsigned* gen, unsigned target) {
  __syncthreads();   // all compute writes of this block issued & drained
  const int t = threadIdx.x;
  if (t == 0) {
    __threadfence();   // release: write back prior global writes before flag
    __hip_atomic_store(&flags[blockIdx.x * 32], target, __ATOMIC_RELAXED, __HIP_MEMORY_SCOPE_AGENT);
  }
  if (blockIdx.x == 0) {
    if (t < SCAN_WGS) {
      while (__hip_atomic_load(&flags[t * 32], __ATOMIC_RELAXED, __HIP_MEMORY_SCOPE_AGENT) < target)
        __builtin_amdgcn_s_sleep(1);
    }
    __syncthreads();   // all flags observed
    if (t == 0)
      __hip_atomic_store(gen, target, __ATOMIC_RELAXED, __HIP_MEMORY_SCOPE_AGENT);
  } else {
    if (t == 0) {
      while (__hip_atomic_load(gen, __ATOMIC_RELAXED, __HIP_MEMORY_SCOPE_AGENT) < target)
        __builtin_amdgcn_s_sleep(1);
    }
  }
  if (t == 0) __threadfence();   // acquire: invalidate stale L1/L2 before h reads
  __syncthreads();
}

__global__ __launch_bounds__(256) void lstm_scan(
    const float* __restrict__ xg,     // (2048, 3072): row = t*4+b
    const float* __restrict__ Whh,    // (3072, 768) fp32
    float* __restrict__ hstate,       // 2 * 3072 floats, (k,b) layout, pre-zeroed
    _Float16* __restrict__ hist,      // (2048, 768) fp16, row = t*4+b
    unsigned* __restrict__ bar)       // flags[96*32] + gen at [3072], pre-zeroed
{
  __shared__ __align__(16) float hbuf[H_SZ * 4];   // [k][b]
  __shared__ __align__(16) float red[4][8][4][4];  // [gate][c][q][b]
  __shared__ float actv[4][8][4];                  // [gate][c][b]
  __shared__ float cst[8][4];

  const int t = threadIdx.x, lane = t & 63, wv = t >> 6;
  const int j0 = blockIdx.x * 8;
  unsigned* flags = bar;
  unsigned* gen = bar + 3072;

  // preload W_hh slice into registers: w[c][kk] = Whh[wv*768 + j0 + c][kk*64 + lane]
  float wreg[8][12];
#pragma unroll
  for (int c = 0; c < 8; ++c)
#pragma unroll
    for (int kk = 0; kk < 12; ++kk)
      wreg[c][kk] = Whh[(size_t)(wv * H_SZ + j0 + c) * H_SZ + kk * 64 + lane];

  if (t < 32) cst[t >> 2][t & 3] = 0.f;

  const int g_ = t >> 5, c_ = (t >> 2) & 7, b_ = t & 3;

  for (int step = 0; step < T_SZ; ++step) {
    float xgv = 0.f;
    if (t < 128)  // prefetch xg before the barrier (independent of h)
      xgv = xg[(size_t)((step << 2) + b_) * G4 + g_ * H_SZ + j0 + c_];

    grid_barrier(flags, gen, (unsigned)(step + 1));

    const float* hprev = hstate + ((step & 1) ? 3072 : 0);
    {
      const float4* s4 = (const float4*)hprev;
      float4* d4 = (float4*)hbuf;
#pragma unroll
      for (int i = 0; i < 3; ++i) d4[i * 256 + t] = s4[i * 256 + t];
    }
    __syncthreads();

    float4 acc[8];
#pragma unroll
    for (int c = 0; c < 8; ++c) acc[c] = make_float4(0.f, 0.f, 0.f, 0.f);
#pragma unroll
    for (int kk = 0; kk < 12; ++kk) {
      float4 h4 = *(const float4*)&hbuf[(kk * 64 + lane) * 4];
#pragma unroll
      for (int c = 0; c < 8; ++c) {
        float wf = wreg[c][kk];
        acc[c].x = fmaf(wf, h4.x, acc[c].x);
        acc[c].y = fmaf(wf, h4.y, acc[c].y);
        acc[c].z = fmaf(wf, h4.z, acc[c].z);
        acc[c].w = fmaf(wf, h4.w, acc[c].w);
      }
    }
    // butterfly reduce within aligned 16-lane groups
#pragma unroll
    for (int mask = 1; mask <= 8; mask <<= 1) {
#pragma unroll
      for (int c = 0; c < 8; ++c) {
        acc[c].x += __shfl_xor(acc[c].x, mask, 64);
        acc[c].y += __shfl_xor(acc[c].y, mask, 64);
        acc[c].z += __shfl_xor(acc[c].z, mask, 64);
        acc[c].w += __shfl_xor(acc[c].w, mask, 64);
      }
    }
    if ((lane & 15) == 0) {
      int q = lane >> 4;
#pragma unroll
      for (int c = 0; c < 8; ++c) *(float4*)&red[wv][c][q][0] = acc[c];
    }
    __syncthreads();

    if (t < 128) {
      float s = red[g_][c_][0][b_] + red[g_][c_][1][b_] + red[g_][c_][2][b_] + red[g_][c_][3][b_] + xgv;
      float a;
      if (g_ == 2) a = tanhf(s);
      else         a = 1.f / (1.f + expf(-s));
      actv[g_][c_][b_] = a;
    }
    __syncthreads();

    if (t < 32) {
      int c = t >> 2, b = t & 3;
      float iv = actv[0][c][b], fv = actv[1][c][b], gv = actv[2][c][b], ov = actv[3][c][b];
      float cn = fv * cst[c][b] + iv * gv;
      cst[c][b] = cn;
      float hn = ov * tanhf(cn);
      float* hnext = hstate + (((step + 1) & 1) ? 3072 : 0);
      hnext[(j0 + c) * 4 + b] = hn;
      hist[(size_t)((step << 2) + b) * H_SZ + j0 + c] = (_Float16)hn;
    }
    // next iteration's grid_barrier provides the ordering before re-reads
  }
}

// ---------------- launcher ----------------

extern "C" void kernel_launch(void* const* d_in, const int* in_sizes, int n_in,
                              void* d_out, int out_size, void* d_ws, size_t ws_size,
                              hipStream_t stream) {
  const float* reps   = (const float*)d_in[0];
  const float* W_ih   = (const float*)d_in[1];
  const float* W_hh   = (const float*)d_in[2];
  const float* bias   = (const float*)d_in[3];
  const float* head_w = (const float*)d_in[4];
  const float* head_b = (const float*)d_in[5];
  float* out = (float*)d_out;

  char* ws = (char*)d_ws;
  _Float16* A0h    = (_Float16*)(ws + 0);            //  3,145,728 B
  _Float16* Wih_h  = (_Float16*)(ws + 3145728);      //  9,437,184 B (both layers)
  _Float16* Whead  = (_Float16*)(ws + 12582912);     // 77,266,944 B (padded)
  float*    xg     = (float*)   (ws + 89849856);     // 25,165,824 B (reused for both layers)
  _Float16* h0hist = (_Float16*)(ws + 115015680);    //  3,145,728 B
  _Float16* h1hist = (_Float16*)(ws + 118161408);    //  3,145,728 B
  float*    hstate = (float*)   (ws + 121307136);    //     24,576 B
  unsigned* bar    = (unsigned*)(ws + 121331712);    //     12,416 B (flags 96*128B + gen)

  // conversions
  hipLaunchKernelGGL(conv_A0,   dim3(1024), dim3(256), 0, stream, reps, A0h);
  hipLaunchKernelGGL(conv_cast, dim3(2048), dim3(256), 0, stream, W_ih, Wih_h, 2 * G4 * H_SZ);
  hipLaunchKernelGGL(conv_head, dim3(4096), dim3(256), 0, stream, head_w, Whead);

  // xg0 = A0 * Wih0^T + b0
  hipLaunchKernelGGL(gemm_bt_f16, dim3(16, 24), dim3(256), 0, stream,
                     A0h, Wih_h, bias, xg, M_SZ, G4, H_SZ, 0, G4);

  // layer 0 scan (plain launch; 96 blocks co-resident by capacity)
  hipMemsetAsync(hstate, 0, 24576, stream);
  hipMemsetAsync(bar, 0, 12416, stream);
  hipLaunchKernelGGL(lstm_scan, dim3(SCAN_WGS), dim3(256), 0, stream,
                     xg, W_hh, hstate, h0hist, bar);

  // xg1 = h0 * Wih1^T + b1
  hipLaunchKernelGGL(gemm_bt_f16, dim3(16, 24), dim3(256), 0, stream,
                     h0hist, Wih_h + (size_t)G4 * H_SZ, bias + G4, xg, M_SZ, G4, H_SZ, 0, G4);

  // layer 1 scan
  hipMemsetAsync(hstate, 0, 24576, stream);
  hipMemsetAsync(bar, 0, 12416, stream);
  hipLaunchKernelGGL(lstm_scan, dim3(SCAN_WGS), dim3(256), 0, stream,
                     xg, W_hh + (size_t)G4 * H_SZ, hstate, h1hist, bar);

  // logits = h1 * head_w^T + head_b  (padded N, permuted store into (B,T,V))
  hipLaunchKernelGGL(gemm_bt_f16, dim3(16, 393), dim3(256), 0, stream,
                     h1hist, Whead, head_b, out, M_SZ, V_PAD, H_SZ, 1, V_SZ);
}

// Round 6
// 5575.201 us; speedup vs baseline: 2.9421x; 1.5702x over previous
//
#include <hip/hip_runtime.h>
#include <hip/hip_fp16.h>
#include <cstdint>

#define B_SZ 4
#define T_SZ 512
#define D_SZ 768
#define H_SZ 768
#define G4   3072           // 4*H
#define V_SZ 50257
#define V_PAD 50304         // 393*128
#define M_SZ 2048           // T*B
#define SCAN_WGS 96

using half8 = __attribute__((ext_vector_type(8))) _Float16;
using f32x4 = __attribute__((ext_vector_type(4))) float;

// ---------------- conversion kernels ----------------

__global__ void conv_A0(const float* __restrict__ reps, _Float16* __restrict__ A0) {
  // A0[(t*4+b)*768 + k] = reps[(b*512 + t)*768 + k]
  int idx = blockIdx.x * blockDim.x + threadIdx.x;
  const int total = M_SZ * D_SZ;
  for (; idx < total; idx += gridDim.x * blockDim.x) {
    int k = idx % D_SZ, m = idx / D_SZ;
    int t = m >> 2, b = m & 3;
    A0[idx] = (_Float16)reps[(b * T_SZ + t) * D_SZ + k];
  }
}

__global__ void conv_cast(const float* __restrict__ src, _Float16* __restrict__ dst, int n) {
  int idx = blockIdx.x * blockDim.x + threadIdx.x;
  for (; idx < n; idx += gridDim.x * blockDim.x) dst[idx] = (_Float16)src[idx];
}

__global__ void conv_head(const float* __restrict__ w, _Float16* __restrict__ dst) {
  int idx = blockIdx.x * blockDim.x + threadIdx.x;
  const int total = V_PAD * H_SZ;
  for (; idx < total; idx += gridDim.x * blockDim.x) {
    int n = idx / H_SZ, k = idx % H_SZ;
    dst[idx] = (n < V_SZ) ? (_Float16)w[n * H_SZ + k] : (_Float16)0.f;
  }
}

// ---------------- f16 MFMA GEMM: C[m][n] = sum_k A[m][k]*B[n][k] + bias[n] ----------------
// A: M x K fp16 row-major, B: N x K fp16 row-major ("B^T input" form).
// mode 0: C row-major M x N fp32.  mode 1: head output C[(b*T + t)*V_SZ + n], m = t*4+b, guard n < Nreal.

__global__ __launch_bounds__(256) void gemm_bt_f16(
    const _Float16* __restrict__ A, const _Float16* __restrict__ B,
    const float* __restrict__ bias, float* __restrict__ C,
    int M, int N, int K, int mode, int Nreal)
{
  __shared__ __align__(16) _Float16 As[128][32];
  __shared__ __align__(16) _Float16 Bs[128][32];
  const int t = threadIdx.x;
  const int lane = t & 63, w = t >> 6;
  const int wr = w >> 1, wc = w & 1;
  const int m0 = blockIdx.x * 128, n0 = blockIdx.y * 128;

  f32x4 acc[4][4] = {};

  const int srow = t >> 2;            // 0..63
  const int scol = (t & 3) * 8;       // half-element offset within 32

  for (int k0 = 0; k0 < K; k0 += 32) {
    uint4 av0 = *(const uint4*)&A[(size_t)(m0 + srow) * K + k0 + scol];
    uint4 av1 = *(const uint4*)&A[(size_t)(m0 + 64 + srow) * K + k0 + scol];
    uint4 bv0 = *(const uint4*)&B[(size_t)(n0 + srow) * K + k0 + scol];
    uint4 bv1 = *(const uint4*)&B[(size_t)(n0 + 64 + srow) * K + k0 + scol];
    __syncthreads();                  // previous iter's frag reads done
    *(uint4*)&As[srow][scol]      = av0;
    *(uint4*)&As[64 + srow][scol] = av1;
    *(uint4*)&Bs[srow][scol]      = bv0;
    *(uint4*)&Bs[64 + srow][scol] = bv1;
    __syncthreads();

    const int fr = lane & 15, k8 = (lane >> 4) * 8;
    half8 af[4], bf[4];
#pragma unroll
    for (int i = 0; i < 4; ++i) {
      af[i] = *(const half8*)&As[wr * 64 + i * 16 + fr][k8];
      bf[i] = *(const half8*)&Bs[wc * 64 + i * 16 + fr][k8];
    }
#pragma unroll
    for (int i = 0; i < 4; ++i)
#pragma unroll
      for (int j = 0; j < 4; ++j)
        acc[i][j] = __builtin_amdgcn_mfma_f32_16x16x32_f16(af[i], bf[j], acc[i][j], 0, 0, 0);
  }

  const int fr = lane & 15, rq = lane >> 4;
#pragma unroll
  for (int i = 0; i < 4; ++i) {
#pragma unroll
    for (int j = 0; j < 4; ++j) {
      int n = n0 + wc * 64 + j * 16 + fr;
      if (n >= Nreal) continue;
      float bv = bias[n];
#pragma unroll
      for (int r = 0; r < 4; ++r) {
        int m = m0 + wr * 64 + i * 16 + rq * 4 + r;
        float v = acc[i][j][r] + bv;
        if (mode == 0) {
          C[(size_t)m * N + n] = v;
        } else {
          int tt = m >> 2, bb = m & 3;
          C[(size_t)(bb * T_SZ + tt) * V_SZ + n] = v;
        }
      }
    }
  }
}

// ---------------- persistent LSTM scan (one layer), plain launch ----------------
// 96 WGs x 256 threads (co-resident by capacity on 256 CUs).
// One-hop all-atomic exchange, zero fences:
//  - h exchanged via hxchg[2][3072] (parity double-buffer). Block j's 32
//    values live in its own 128B line; written as RELAXED agent-scope 4B
//    atomic stores (sc1 write-through to coherence point).
//  - data->flag order: __syncthreads() emits s_waitcnt vmcnt(0) [HIP-compiler],
//    so data stores are ack'd at the coherence point before the flag store
//    issues. Any reader that observes the flag observes the data.
//  - EVERY block polls all 96 flags directly (t<96, one each, RELAXED loads)
//    -- no block-0 fan-in hop, no gen broadcast.
//  - readers pull h with RELAXED 8B atomic loads (6/thread) into LDS.
// Flags monotone (step+1); flags+hxchg memset 0 before each scan launch.

__global__ __launch_bounds__(256) void lstm_scan(
    const float* __restrict__ xg,     // (2048, 3072): row = t*4+b
    const float* __restrict__ Whh,    // (3072, 768) fp32
    float* __restrict__ hxchg,        // [2][3072] floats, (k,b) layout, pre-zeroed
    _Float16* __restrict__ hist,      // (2048, 768) fp16, row = t*4+b
    unsigned* __restrict__ flags)     // [96*32], pre-zeroed
{
  __shared__ __align__(16) float hbuf[H_SZ * 4];   // [k][b]
  __shared__ __align__(16) float red[4][8][4][4];  // [gate][c][q][b]
  __shared__ float actv[4][8][4];                  // [gate][c][b]
  __shared__ float cst[8][4];

  const int t = threadIdx.x, lane = t & 63, wv = t >> 6;
  const int j0 = blockIdx.x * 8;

  // preload W_hh slice into registers: w[c][kk] = Whh[wv*768 + j0 + c][kk*64 + lane]
  float wreg[8][12];
#pragma unroll
  for (int c = 0; c < 8; ++c)
#pragma unroll
    for (int kk = 0; kk < 12; ++kk)
      wreg[c][kk] = Whh[(size_t)(wv * H_SZ + j0 + c) * H_SZ + kk * 64 + lane];

  if (t < 32) cst[t >> 2][t & 3] = 0.f;

  const int g_ = t >> 5, c_ = (t >> 2) & 7, b_ = t & 3;

  for (int step = 0; step < T_SZ; ++step) {
    float xgv = 0.f;
    if (t < 128)  // prefetch xg before the sync (independent of h)
      xgv = xg[(size_t)((step << 2) + b_) * G4 + g_ * H_SZ + j0 + c_];

    // drain previous tail's data stores (s_waitcnt vmcnt(0) before s_barrier)
    __syncthreads();
    if (t == 0)
      __hip_atomic_store(&flags[blockIdx.x * 32], (unsigned)(step + 1),
                         __ATOMIC_RELAXED, __HIP_MEMORY_SCOPE_AGENT);
    if (t < SCAN_WGS) {
      while (__hip_atomic_load(&flags[t * 32], __ATOMIC_RELAXED, __HIP_MEMORY_SCOPE_AGENT)
             < (unsigned)(step + 1))
        __builtin_amdgcn_s_sleep(1);
    }
    __syncthreads();

    // gather h[step] (parity step&1) into LDS via relaxed 8B atomic loads
    {
      const unsigned long long* src =
          (const unsigned long long*)(hxchg + ((step & 1) ? 3072 : 0));
      unsigned long long* dst = (unsigned long long*)hbuf;
#pragma unroll
      for (int i = 0; i < 6; ++i) {
        int slot = t + i * 256;   // 1536 slots total
        dst[slot] = __hip_atomic_load(&src[slot], __ATOMIC_RELAXED, __HIP_MEMORY_SCOPE_AGENT);
      }
    }
    __syncthreads();

    float4 acc[8];
#pragma unroll
    for (int c = 0; c < 8; ++c) acc[c] = make_float4(0.f, 0.f, 0.f, 0.f);
#pragma unroll
    for (int kk = 0; kk < 12; ++kk) {
      float4 h4 = *(const float4*)&hbuf[(kk * 64 + lane) * 4];
#pragma unroll
      for (int c = 0; c < 8; ++c) {
        float wf = wreg[c][kk];
        acc[c].x = fmaf(wf, h4.x, acc[c].x);
        acc[c].y = fmaf(wf, h4.y, acc[c].y);
        acc[c].z = fmaf(wf, h4.z, acc[c].z);
        acc[c].w = fmaf(wf, h4.w, acc[c].w);
      }
    }
    // butterfly reduce within aligned 16-lane groups
#pragma unroll
    for (int mask = 1; mask <= 8; mask <<= 1) {
#pragma unroll
      for (int c = 0; c < 8; ++c) {
        acc[c].x += __shfl_xor(acc[c].x, mask, 64);
        acc[c].y += __shfl_xor(acc[c].y, mask, 64);
        acc[c].z += __shfl_xor(acc[c].z, mask, 64);
        acc[c].w += __shfl_xor(acc[c].w, mask, 64);
      }
    }
    if ((lane & 15) == 0) {
      int q = lane >> 4;
#pragma unroll
      for (int c = 0; c < 8; ++c) *(float4*)&red[wv][c][q][0] = acc[c];
    }
    __syncthreads();

    if (t < 128) {
      float s = red[g_][c_][0][b_] + red[g_][c_][1][b_] + red[g_][c_][2][b_] + red[g_][c_][3][b_] + xgv;
      float a;
      if (g_ == 2) a = tanhf(s);
      else         a = 1.f / (1.f + expf(-s));
      actv[g_][c_][b_] = a;
    }
    __syncthreads();

    if (t < 32) {
      int c = t >> 2, b = t & 3;
      float iv = actv[0][c][b], fv = actv[1][c][b], gv = actv[2][c][b], ov = actv[3][c][b];
      float cn = fv * cst[c][b] + iv * gv;
      cst[c][b] = cn;
      float hn = ov * tanhf(cn);
      float* hnext = hxchg + (((step + 1) & 1) ? 3072 : 0);
      __hip_atomic_store(&hnext[(j0 + c) * 4 + b], hn,
                         __ATOMIC_RELAXED, __HIP_MEMORY_SCOPE_AGENT);
      hist[(size_t)((step << 2) + b) * H_SZ + j0 + c] = (_Float16)hn;
    }
    // next iteration's __syncthreads drains these stores before the flag
  }
}

// ---------------- launcher ----------------

extern "C" void kernel_launch(void* const* d_in, const int* in_sizes, int n_in,
                              void* d_out, int out_size, void* d_ws, size_t ws_size,
                              hipStream_t stream) {
  const float* reps   = (const float*)d_in[0];
  const float* W_ih   = (const float*)d_in[1];
  const float* W_hh   = (const float*)d_in[2];
  const float* bias   = (const float*)d_in[3];
  const float* head_w = (const float*)d_in[4];
  const float* head_b = (const float*)d_in[5];
  float* out = (float*)d_out;

  char* ws = (char*)d_ws;
  _Float16* A0h    = (_Float16*)(ws + 0);            //  3,145,728 B
  _Float16* Wih_h  = (_Float16*)(ws + 3145728);      //  9,437,184 B (both layers)
  _Float16* Whead  = (_Float16*)(ws + 12582912);     // 77,266,944 B (padded)
  float*    xg     = (float*)   (ws + 89849856);     // 25,165,824 B (reused for both layers)
  _Float16* h0hist = (_Float16*)(ws + 115015680);    //  3,145,728 B
  _Float16* h1hist = (_Float16*)(ws + 118161408);    //  3,145,728 B
  float*    hxchg  = (float*)   (ws + 121307136);    //     24,576 B ([2][3072])
  unsigned* flags  = (unsigned*)(ws + 121331712);    //     12,288 B (96 * 128B)

  // conversions
  hipLaunchKernelGGL(conv_A0,   dim3(1024), dim3(256), 0, stream, reps, A0h);
  hipLaunchKernelGGL(conv_cast, dim3(2048), dim3(256), 0, stream, W_ih, Wih_h, 2 * G4 * H_SZ);
  hipLaunchKernelGGL(conv_head, dim3(4096), dim3(256), 0, stream, head_w, Whead);

  // xg0 = A0 * Wih0^T + b0
  hipLaunchKernelGGL(gemm_bt_f16, dim3(16, 24), dim3(256), 0, stream,
                     A0h, Wih_h, bias, xg, M_SZ, G4, H_SZ, 0, G4);

  // layer 0 scan (plain launch; 96 blocks co-resident by capacity)
  hipMemsetAsync(hxchg, 0, 24576, stream);
  hipMemsetAsync(flags, 0, 12288, stream);
  hipLaunchKernelGGL(lstm_scan, dim3(SCAN_WGS), dim3(256), 0, stream,
                     xg, W_hh, hxchg, h0hist, flags);

  // xg1 = h0 * Wih1^T + b1
  hipLaunchKernelGGL(gemm_bt_f16, dim3(16, 24), dim3(256), 0, stream,
                     h0hist, Wih_h + (size_t)G4 * H_SZ, bias + G4, xg, M_SZ, G4, H_SZ, 0, G4);

  // layer 1 scan
  hipMemsetAsync(hxchg, 0, 24576, stream);
  hipMemsetAsync(flags, 0, 12288, stream);
  hipLaunchKernelGGL(lstm_scan, dim3(SCAN_WGS), dim3(256), 0, stream,
                     xg, W_hh + (size_t)G4 * H_SZ, hxchg, h1hist, flags);

  // logits = h1 * head_w^T + head_b  (padded N, permuted store into (B,T,V))
  hipLaunchKernelGGL(gemm_bt_f16, dim3(16, 393), dim3(256), 0, stream,
                     h1hist, Whead, head_b, out, M_SZ, V_PAD, H_SZ, 1, V_SZ);
}

// Round 7
// 4634.406 us; speedup vs baseline: 3.5393x; 1.2030x over previous
//
#include <hip/hip_runtime.h>
#include <hip/hip_fp16.h>
#include <cstdint>

#define B_SZ 4
#define T_SZ 512
#define D_SZ 768
#define H_SZ 768
#define G4   3072           // 4*H
#define V_SZ 50257
#define V_PAD 50304         // 393*128
#define M_SZ 2048           // T*B
#define FUSE_WGS 192        // 96 layer-0 + 96 layer-1

using half8 = __attribute__((ext_vector_type(8))) _Float16;
using f32x4 = __attribute__((ext_vector_type(4))) float;

// ---------------- conversion kernels ----------------

__global__ void conv_A0(const float* __restrict__ reps, _Float16* __restrict__ A0) {
  // A0[(t*4+b)*768 + k] = reps[(b*512 + t)*768 + k]
  int idx = blockIdx.x * blockDim.x + threadIdx.x;
  const int total = M_SZ * D_SZ;
  for (; idx < total; idx += gridDim.x * blockDim.x) {
    int k = idx % D_SZ, m = idx / D_SZ;
    int t = m >> 2, b = m & 3;
    A0[idx] = (_Float16)reps[(b * T_SZ + t) * D_SZ + k];
  }
}

__global__ void conv_cast(const float* __restrict__ src, _Float16* __restrict__ dst, int n) {
  int idx = blockIdx.x * blockDim.x + threadIdx.x;
  for (; idx < n; idx += gridDim.x * blockDim.x) dst[idx] = (_Float16)src[idx];
}

__global__ void conv_head(const float* __restrict__ w, _Float16* __restrict__ dst) {
  int idx = blockIdx.x * blockDim.x + threadIdx.x;
  const int total = V_PAD * H_SZ;
  for (; idx < total; idx += gridDim.x * blockDim.x) {
    int n = idx / H_SZ, k = idx % H_SZ;
    dst[idx] = (n < V_SZ) ? (_Float16)w[n * H_SZ + k] : (_Float16)0.f;
  }
}

// ---------------- f16 MFMA GEMM: C[m][n] = sum_k A[m][k]*B[n][k] + bias[n] ----------------

__global__ __launch_bounds__(256) void gemm_bt_f16(
    const _Float16* __restrict__ A, const _Float16* __restrict__ B,
    const float* __restrict__ bias, float* __restrict__ C,
    int M, int N, int K, int mode, int Nreal)
{
  __shared__ __align__(16) _Float16 As[128][32];
  __shared__ __align__(16) _Float16 Bs[128][32];
  const int t = threadIdx.x;
  const int lane = t & 63, w = t >> 6;
  const int wr = w >> 1, wc = w & 1;
  const int m0 = blockIdx.x * 128, n0 = blockIdx.y * 128;

  f32x4 acc[4][4] = {};

  const int srow = t >> 2;
  const int scol = (t & 3) * 8;

  for (int k0 = 0; k0 < K; k0 += 32) {
    uint4 av0 = *(const uint4*)&A[(size_t)(m0 + srow) * K + k0 + scol];
    uint4 av1 = *(const uint4*)&A[(size_t)(m0 + 64 + srow) * K + k0 + scol];
    uint4 bv0 = *(const uint4*)&B[(size_t)(n0 + srow) * K + k0 + scol];
    uint4 bv1 = *(const uint4*)&B[(size_t)(n0 + 64 + srow) * K + k0 + scol];
    __syncthreads();
    *(uint4*)&As[srow][scol]      = av0;
    *(uint4*)&As[64 + srow][scol] = av1;
    *(uint4*)&Bs[srow][scol]      = bv0;
    *(uint4*)&Bs[64 + srow][scol] = bv1;
    __syncthreads();

    const int fr = lane & 15, k8 = (lane >> 4) * 8;
    half8 af[4], bf[4];
#pragma unroll
    for (int i = 0; i < 4; ++i) {
      af[i] = *(const half8*)&As[wr * 64 + i * 16 + fr][k8];
      bf[i] = *(const half8*)&Bs[wc * 64 + i * 16 + fr][k8];
    }
#pragma unroll
    for (int i = 0; i < 4; ++i)
#pragma unroll
      for (int j = 0; j < 4; ++j)
        acc[i][j] = __builtin_amdgcn_mfma_f32_16x16x32_f16(af[i], bf[j], acc[i][j], 0, 0, 0);
  }

  const int fr = lane & 15, rq = lane >> 4;
#pragma unroll
  for (int i = 0; i < 4; ++i) {
#pragma unroll
    for (int j = 0; j < 4; ++j) {
      int n = n0 + wc * 64 + j * 16 + fr;
      if (n >= Nreal) continue;
      float bv = bias[n];
#pragma unroll
      for (int r = 0; r < 4; ++r) {
        int m = m0 + wr * 64 + i * 16 + rq * 4 + r;
        float v = acc[i][j][r] + bv;
        if (mode == 0) {
          C[(size_t)m * N + n] = v;
        } else {
          int tt = m >> 2, bb = m & 3;
          C[(size_t)(bb * T_SZ + tt) * V_SZ + n] = v;
        }
      }
    }
  }
}

// ---------------- fused 2-layer pipelined LSTM scan ----------------
// 192 blocks x 256 threads. Blocks 0..95: layer 0; 96..191: layer 1 (lagged 1).
// Epoch e (0..512): L0 computes step e (e<=511); L1 computes step e-1 (e>=1),
// consuming H0[e-1] (published this epoch) + carry H1[e-2]. xg1 computed
// in-kernel: W_ih1 slice in registers, second matvec. 513 epochs total.
// Sync: round-6-proven relaxed agent-scope flags, 192 lines. Publication at
// epoch TAIL: wave 0 (owns all 32 h-stores) inline s_waitcnt vmcnt(0) then
// lane 0 stores flag = e+2 ("my epoch-e reads+writes done"). Poll at epoch
// e>=1: t<192 wait flags >= e+1. Epoch 0 needs no poll (memset state).
// Parity: reads at epoch e use hx[e&1]; writes go to hx[(e+1)&1].

__global__ __launch_bounds__(256) void lstm_fused(
    const float* __restrict__ xg0,    // (2048,3072) layer-0 input projections
    const float* __restrict__ Wih1,   // (3072,768) fp32 layer-1 input weights
    const float* __restrict__ Whh,    // (2,3072,768) fp32
    const float* __restrict__ bias,   // (2,3072) fp32
    float* __restrict__ hx0,          // [2][3072] (k,b), pre-zeroed
    float* __restrict__ hx1,          // [2][3072] (k,b), pre-zeroed
    _Float16* __restrict__ h1hist,    // (2048,768) fp16, row = t*4+b
    unsigned* __restrict__ flags)     // [192*32], pre-zeroed
{
  __shared__ __align__(16) float h0buf[H_SZ * 4];  // [k][b]
  __shared__ __align__(16) float h1buf[H_SZ * 4];  // [k][b] (layer-1 carry)
  __shared__ __align__(16) float red[4][8][4][4];  // [gate][c][q][b]
  __shared__ float actv[4][8][4];                  // [gate][c][b]
  __shared__ float cst[8][4];

  const int t = threadIdx.x, lane = t & 63, wv = t >> 6;
  const bool L1 = blockIdx.x >= 96;
  const int lid = L1 ? (blockIdx.x - 96) : blockIdx.x;
  const int j0 = lid * 8;

  const float* WhhL = Whh + (L1 ? (size_t)G4 * H_SZ : 0);

  // W_hh slice in registers
  float wreg[8][12];
#pragma unroll
  for (int c = 0; c < 8; ++c)
#pragma unroll
    for (int kk = 0; kk < 12; ++kk)
      wreg[c][kk] = WhhL[(size_t)(wv * H_SZ + j0 + c) * H_SZ + kk * 64 + lane];

  // layer-1: W_ih1 slice in registers (x-projection)
  float wreg2[8][12];
  if (L1) {
#pragma unroll
    for (int c = 0; c < 8; ++c)
#pragma unroll
      for (int kk = 0; kk < 12; ++kk)
        wreg2[c][kk] = Wih1[(size_t)(wv * H_SZ + j0 + c) * H_SZ + kk * 64 + lane];
  }

  const int g_ = t >> 5, c_ = (t >> 2) & 7, b_ = t & 3;

  float breg = 0.f;
  if (L1 && t < 128) breg = bias[G4 + g_ * H_SZ + j0 + c_];

  if (t < 32) cst[t >> 2][t & 3] = 0.f;

  const int elim = L1 ? 513 : 512;
  for (int e = 0; e < elim; ++e) {
    float xgv = 0.f;
    if (!L1 && t < 128)  // prefetch xg0[e] before the poll (independent)
      xgv = xg0[(size_t)((e << 2) + b_) * G4 + g_ * H_SZ + j0 + c_];

    if (e >= 1) {
      if (t < FUSE_WGS) {
        while (__hip_atomic_load(&flags[t * 32], __ATOMIC_RELAXED, __HIP_MEMORY_SCOPE_AGENT)
               < (unsigned)(e + 1))
          __builtin_amdgcn_s_sleep(1);
      }
    }
    __syncthreads();

    const bool act = !L1 || (e >= 1);

    if (act) {
      // gather h (parity e&1) into LDS via relaxed 8B atomic loads
      {
        const unsigned long long* s0 =
            (const unsigned long long*)(hx0 + ((e & 1) ? 3072 : 0));
        unsigned long long* d0 = (unsigned long long*)h0buf;
#pragma unroll
        for (int i = 0; i < 6; ++i)
          d0[t + i * 256] = __hip_atomic_load(&s0[t + i * 256], __ATOMIC_RELAXED, __HIP_MEMORY_SCOPE_AGENT);
        if (L1) {
          const unsigned long long* s1 =
              (const unsigned long long*)(hx1 + ((e & 1) ? 3072 : 0));
          unsigned long long* d1 = (unsigned long long*)h1buf;
#pragma unroll
          for (int i = 0; i < 6; ++i)
            d1[t + i * 256] = __hip_atomic_load(&s1[t + i * 256], __ATOMIC_RELAXED, __HIP_MEMORY_SCOPE_AGENT);
        }
      }
      __syncthreads();

      float4 acc[8];
#pragma unroll
      for (int c = 0; c < 8; ++c) acc[c] = make_float4(0.f, 0.f, 0.f, 0.f);

      if (!L1) {
#pragma unroll
        for (int kk = 0; kk < 12; ++kk) {
          float4 h4 = *(const float4*)&h0buf[(kk * 64 + lane) * 4];
#pragma unroll
          for (int c = 0; c < 8; ++c) {
            float wf = wreg[c][kk];
            acc[c].x = fmaf(wf, h4.x, acc[c].x);
            acc[c].y = fmaf(wf, h4.y, acc[c].y);
            acc[c].z = fmaf(wf, h4.z, acc[c].z);
            acc[c].w = fmaf(wf, h4.w, acc[c].w);
          }
        }
      } else {
#pragma unroll
        for (int kk = 0; kk < 12; ++kk) {
          float4 x4 = *(const float4*)&h0buf[(kk * 64 + lane) * 4];  // x = H0
          float4 h4 = *(const float4*)&h1buf[(kk * 64 + lane) * 4];  // carry H1
#pragma unroll
          for (int c = 0; c < 8; ++c) {
            float wx = wreg2[c][kk], wh = wreg[c][kk];
            acc[c].x = fmaf(wx, x4.x, fmaf(wh, h4.x, acc[c].x));
            acc[c].y = fmaf(wx, x4.y, fmaf(wh, h4.y, acc[c].y));
            acc[c].z = fmaf(wx, x4.z, fmaf(wh, h4.z, acc[c].z));
            acc[c].w = fmaf(wx, x4.w, fmaf(wh, h4.w, acc[c].w));
          }
        }
      }

      // butterfly reduce within aligned 16-lane groups
#pragma unroll
      for (int mask = 1; mask <= 8; mask <<= 1) {
#pragma unroll
        for (int c = 0; c < 8; ++c) {
          acc[c].x += __shfl_xor(acc[c].x, mask, 64);
          acc[c].y += __shfl_xor(acc[c].y, mask, 64);
          acc[c].z += __shfl_xor(acc[c].z, mask, 64);
          acc[c].w += __shfl_xor(acc[c].w, mask, 64);
        }
      }
      if ((lane & 15) == 0) {
        int q = lane >> 4;
#pragma unroll
        for (int c = 0; c < 8; ++c) *(float4*)&red[wv][c][q][0] = acc[c];
      }
      __syncthreads();

      if (t < 128) {
        float s = red[g_][c_][0][b_] + red[g_][c_][1][b_] + red[g_][c_][2][b_] + red[g_][c_][3][b_]
                + (L1 ? breg : xgv);
        float a;
        if (g_ == 2) a = tanhf(s);
        else         a = 1.f / (1.f + expf(-s));
        actv[g_][c_][b_] = a;
      }
      __syncthreads();

      if (t < 32) {
        int c = t >> 2, b = t & 3;
        float iv = actv[0][c][b], fv = actv[1][c][b], gv = actv[2][c][b], ov = actv[3][c][b];
        float cn = fv * cst[c][b] + iv * gv;
        cst[c][b] = cn;
        float hn = ov * tanhf(cn);
        float* hnext = (L1 ? hx1 : hx0) + (((e + 1) & 1) ? 3072 : 0);
        __hip_atomic_store(&hnext[(j0 + c) * 4 + b], hn,
                           __ATOMIC_RELAXED, __HIP_MEMORY_SCOPE_AGENT);
        if (L1)
          h1hist[(size_t)(((e - 1) << 2) + b) * H_SZ + j0 + c] = (_Float16)hn;
      }
    }

    // tail publication: wave 0 owns all h-stores; drain then flag
    if (e < 512) {
      if (wv == 0) {
        asm volatile("s_waitcnt vmcnt(0)" ::: "memory");
        if (t == 0)
          __hip_atomic_store(&flags[blockIdx.x * 32], (unsigned)(e + 2),
                             __ATOMIC_RELAXED, __HIP_MEMORY_SCOPE_AGENT);
      }
    }
    // loop-top __syncthreads (after poll) separates this epoch's LDS reads
    // from next epoch's gather writes; hbuf reads end 2 syncs before.
  }
}

// ---------------- launcher ----------------

extern "C" void kernel_launch(void* const* d_in, const int* in_sizes, int n_in,
                              void* d_out, int out_size, void* d_ws, size_t ws_size,
                              hipStream_t stream) {
  const float* reps   = (const float*)d_in[0];
  const float* W_ih   = (const float*)d_in[1];
  const float* W_hh   = (const float*)d_in[2];
  const float* bias   = (const float*)d_in[3];
  const float* head_w = (const float*)d_in[4];
  const float* head_b = (const float*)d_in[5];
  float* out = (float*)d_out;

  char* ws = (char*)d_ws;
  _Float16* A0h    = (_Float16*)(ws + 0);            //  3,145,728 B
  _Float16* Wih_h  = (_Float16*)(ws + 3145728);      //  4,718,592 B (layer 0 only)
  _Float16* Whead  = (_Float16*)(ws + 12582912);     // 77,266,944 B (padded)
  float*    xg0    = (float*)   (ws + 89849856);     // 25,165,824 B
  _Float16* h1hist = (_Float16*)(ws + 115015680);    //  3,145,728 B
  float*    hx0    = (float*)   (ws + 118161408);    //     24,576 B
  float*    hx1    = (float*)   (ws + 118185984);    //     24,576 B
  unsigned* flags  = (unsigned*)(ws + 118210560);    //     24,576 B (192*128B)

  // conversions
  hipLaunchKernelGGL(conv_A0,   dim3(1024), dim3(256), 0, stream, reps, A0h);
  hipLaunchKernelGGL(conv_cast, dim3(1024), dim3(256), 0, stream, W_ih, Wih_h, G4 * D_SZ);
  hipLaunchKernelGGL(conv_head, dim3(4096), dim3(256), 0, stream, head_w, Whead);

  // xg0 = A0 * Wih0^T + b0
  hipLaunchKernelGGL(gemm_bt_f16, dim3(16, 24), dim3(256), 0, stream,
                     A0h, Wih_h, bias, xg0, M_SZ, G4, H_SZ, 0, G4);

  // fused pipelined 2-layer scan (192 blocks co-resident by capacity)
  hipMemsetAsync(hx0, 0, 73728, stream);  // hx0 + hx1 + flags contiguous
  hipLaunchKernelGGL(lstm_fused, dim3(FUSE_WGS), dim3(256), 0, stream,
                     xg0, W_ih + (size_t)G4 * D_SZ, W_hh, bias,
                     hx0, hx1, h1hist, flags);

  // logits = h1 * head_w^T + head_b  (padded N, permuted store into (B,T,V))
  hipLaunchKernelGGL(gemm_bt_f16, dim3(16, 393), dim3(256), 0, stream,
                     h1hist, Whead, head_b, out, M_SZ, V_PAD, H_SZ, 1, V_SZ);
}